// Round 5
// baseline (531.931 us; speedup 1.0000x reference)
//
#include <hip/hip_runtime.h>
#include <hip/hip_bf16.h>
#include <cstdint>
#include <cstddef>

// ---------------------------------------------------------------------------
// NostARHeadAttention: LN -> {Q(last), K} proj -> RoPE(K) -> 1-query attn
// with V-elimination (out_head = v_w_head @ softmax-weighted sum of hs + v_b).
// R4: (1) GEMM epilogue rotates q instead of K (no shfl, no bias, no gmax);
// kb.q-tilde folded into attn_z; __launch_bounds__(256,5) to recover
// occupancy (R3's 128 VGPR cost 6->4 waves/SIMD).  (2) ln+f2bf+sctab+ixhlast
// fused into one prep launch.  11 -> 8 kernels.
// ---------------------------------------------------------------------------

using bf16x8 = __attribute__((ext_vector_type(8))) __bf16;
using f32x4  = __attribute__((ext_vector_type(4))) float;

__device__ __forceinline__ unsigned short f2bf(float f) {
  unsigned u = __float_as_uint(f);
  u += 0x7fffu + ((u >> 16) & 1u);   // RNE
  return (unsigned short)(u >> 16);
}

__device__ __forceinline__ void gld16(const void* g, void* l) {
  __builtin_amdgcn_global_load_lds((__attribute__((address_space(1))) void*)g,
                                   (__attribute__((address_space(3))) void*)l,
                                   16, 0, 0);
}

// ---------------------------------------------------------------------------
// 1. prep: fused ln (blocks 0..16383) + k_w f2bf (16384..20479) +
//    sctab (20480..20735) + ix+hlast (20736..20743).
// ---------------------------------------------------------------------------
__global__ __launch_bounds__(256) void prep_kernel(
    const float* __restrict__ hidden, const int* __restrict__ ids,
    const float* __restrict__ gw, const float* __restrict__ gb,
    const float* __restrict__ kw, unsigned short* __restrict__ hs,
    unsigned short* __restrict__ Wk, float2* __restrict__ tab,
    float* __restrict__ hl) {
  const int blk = blockIdx.x, tid = threadIdx.x;
  const int wave = tid >> 6, lane = tid & 63;

  if (blk < 16384) {                       // ---- LayerNorm row -> bf16
    const size_t row = blk;
    const float* xr = hidden + row * 2048;
    float4 a = ((const float4*)xr)[tid];
    float4 b = ((const float4*)xr)[tid + 256];
    float s  = a.x + a.y + a.z + a.w + b.x + b.y + b.z + b.w;
    float ss = a.x*a.x + a.y*a.y + a.z*a.z + a.w*a.w +
               b.x*b.x + b.y*b.y + b.z*b.z + b.w*b.w;
    for (int m = 1; m < 64; m <<= 1) { s += __shfl_xor(s, m); ss += __shfl_xor(ss, m); }
    __shared__ float rs[4], rss[4];
    if (lane == 0) { rs[wave] = s; rss[wave] = ss; }
    __syncthreads();
    s  = rs[0] + rs[1] + rs[2] + rs[3];
    ss = rss[0] + rss[1] + rss[2] + rss[3];
    const float mu = s * (1.f / 2048.f);
    const float var = ss * (1.f / 2048.f) - mu * mu;
    const float r = rsqrtf(var + 1e-5f);
    const int i0 = tid * 4, i1 = 1024 + tid * 4;
    ushort4 p0 = {f2bf((a.x - mu) * r * gw[i0 + 0] + gb[i0 + 0]),
                  f2bf((a.y - mu) * r * gw[i0 + 1] + gb[i0 + 1]),
                  f2bf((a.z - mu) * r * gw[i0 + 2] + gb[i0 + 2]),
                  f2bf((a.w - mu) * r * gw[i0 + 3] + gb[i0 + 3])};
    ushort4 p1 = {f2bf((b.x - mu) * r * gw[i1 + 0] + gb[i1 + 0]),
                  f2bf((b.y - mu) * r * gw[i1 + 1] + gb[i1 + 1]),
                  f2bf((b.z - mu) * r * gw[i1 + 2] + gb[i1 + 2]),
                  f2bf((b.w - mu) * r * gw[i1 + 3] + gb[i1 + 3])};
    *(ushort4*)(hs + row * 2048 + i0) = p0;
    *(ushort4*)(hs + row * 2048 + i1) = p1;
  } else if (blk < 20480) {                // ---- k_w fp32 -> bf16
    const size_t i = (size_t)(blk - 16384) * 256 + tid;
    float4 v = ((const float4*)kw)[i];
    ushort4 o = {f2bf(v.x), f2bf(v.y), f2bf(v.z), f2bf(v.w)};
    ((ushort4*)Wk)[i] = o;
  } else if (blk < 20736) {                // ---- sin/cos table (8 t / block)
    const int t = (blk - 20480) * 8 + (tid >> 5);
    const int i = tid & 31;
    const float inv = powf(10000.f, -(float)i / 32.f);
    const float ang = (float)t * inv;
    tab[t * 32 + i] = make_float2(sinf(ang), cosf(ang));
  } else {                                 // ---- last-token index + LN
    const int b = blk - 20736;
    int best = -1;
    for (int t = tid; t < 2048; t += 256)
      if (ids[b * 2048 + t] != 50257) best = (t > best) ? t : best;
    for (int m = 1; m < 64; m <<= 1) {
      int o = __shfl_xor(best, m);
      best = (o > best) ? o : best;
    }
    __shared__ int rb[4];
    if (lane == 0) rb[wave] = best;
    __syncthreads();
    int ix = rb[0];
    for (int w = 1; w < 4; ++w) ix = (rb[w] > ix) ? rb[w] : ix;
    ix = (ix < 0) ? 0 : ix;
    const float* xr = hidden + ((size_t)b * 2048 + ix) * 2048;
    float4 a = ((const float4*)xr)[tid];
    float4 c = ((const float4*)xr)[tid + 256];
    float s  = a.x + a.y + a.z + a.w + c.x + c.y + c.z + c.w;
    float ss = a.x*a.x + a.y*a.y + a.z*a.z + a.w*a.w +
               c.x*c.x + c.y*c.y + c.z*c.z + c.w*c.w;
    for (int m = 1; m < 64; m <<= 1) { s += __shfl_xor(s, m); ss += __shfl_xor(ss, m); }
    __shared__ float rs2[4], rss2[4];
    if (lane == 0) { rs2[wave] = s; rss2[wave] = ss; }
    __syncthreads();
    s  = rs2[0] + rs2[1] + rs2[2] + rs2[3];
    ss = rss2[0] + rss2[1] + rss2[2] + rss2[3];
    const float mu = s * (1.f / 2048.f);
    const float var = ss * (1.f / 2048.f) - mu * mu;
    const float r = rsqrtf(var + 1e-5f);
    const int i0 = tid * 4, i1 = 1024 + tid * 4;
    float* yo = hl + (size_t)b * 2048;
    yo[i0 + 0] = (a.x - mu) * r * gw[i0 + 0] + gb[i0 + 0];
    yo[i0 + 1] = (a.y - mu) * r * gw[i0 + 1] + gb[i0 + 1];
    yo[i0 + 2] = (a.z - mu) * r * gw[i0 + 2] + gb[i0 + 2];
    yo[i0 + 3] = (a.w - mu) * r * gw[i0 + 3] + gb[i0 + 3];
    yo[i1 + 0] = (c.x - mu) * r * gw[i1 + 0] + gb[i1 + 0];
    yo[i1 + 1] = (c.y - mu) * r * gw[i1 + 1] + gb[i1 + 1];
    yo[i1 + 2] = (c.z - mu) * r * gw[i1 + 2] + gb[i1 + 2];
    yo[i1 + 3] = (c.w - mu) * r * gw[i1 + 3] + gb[i1 + 3];
  }
}

// ---------------------------------------------------------------------------
// 2. GEMV: Y[8][2048] = X[8][2048] @ W^T + bias (fp32), 512 blocks.
// ---------------------------------------------------------------------------
__global__ __launch_bounds__(256) void gemv8_kernel(const float* __restrict__ X,
                                                    const float* __restrict__ W,
                                                    const float* __restrict__ bias,
                                                    float* __restrict__ Y) {
  const int tid = threadIdx.x, lane = tid & 63, wave = tid >> 6;
  const int e = blockIdx.x * 4 + wave;
  const float* wr = W + (size_t)e * 2048;
  float p[8] = {0, 0, 0, 0, 0, 0, 0, 0};
#pragma unroll
  for (int it = 0; it < 8; ++it) {
    const int k = it * 256 + lane * 4;
    float4 wv = *(const float4*)(wr + k);
#pragma unroll
    for (int b = 0; b < 8; ++b) {
      float4 xv = *(const float4*)(X + b * 2048 + k);
      p[b] += wv.x * xv.x + wv.y * xv.y + wv.z * xv.z + wv.w * xv.w;
    }
  }
#pragma unroll
  for (int b = 0; b < 8; ++b)
    for (int m = 1; m < 64; m <<= 1) p[b] += __shfl_xor(p[b], m);
  if (lane == 0) {
    const float bb = bias[e];
#pragma unroll
    for (int b = 0; b < 8; ++b) Y[(size_t)b * 2048 + e] = p[b] + bb;
  }
}

// ---------------------------------------------------------------------------
// 3. K GEMM + fused q-tilde dot epilogue (no bias, no shfl, no gmax).
//    scores[bh][t] = sum_d K[t,hd] * qtilde[b,h,t,d]  (bias term in attn_z).
// ---------------------------------------------------------------------------
__global__ __launch_bounds__(256, 5) void gemm_kscore_kernel(
    const unsigned short* __restrict__ A, const unsigned short* __restrict__ W,
    const float* __restrict__ qv, const float2* __restrict__ tab,
    float* __restrict__ scores) {
  constexpr int K = 2048;
  __shared__ unsigned short As[128 * 32];
  __shared__ unsigned short Bs[128 * 32];
  const int tid = threadIdx.x;
  const int lane = tid & 63, wave = tid >> 6;
  const int wr = wave >> 1, wc = wave & 1;
  const int bm = blockIdx.x, bn = blockIdx.y;

  const unsigned short* Ap = A + ((size_t)(bm * 128 + (tid >> 2))) * K + (tid & 3) * 8;
  const unsigned short* Bp = W + ((size_t)(bn * 128 + (tid >> 2))) * K + (tid & 3) * 8;
  unsigned short* lA0 = As + wave * 512;
  unsigned short* lA1 = As + 2048 + wave * 512;
  unsigned short* lB0 = Bs + wave * 512;
  unsigned short* lB1 = Bs + 2048 + wave * 512;

  f32x4 acc[4][4];
#pragma unroll
  for (int i = 0; i < 4; ++i)
#pragma unroll
    for (int j = 0; j < 4; ++j) acc[i][j] = (f32x4){0.f, 0.f, 0.f, 0.f};

  const unsigned short* aPtr[4];
  const unsigned short* bPtr[4];
#pragma unroll
  for (int mi = 0; mi < 4; ++mi)
    aPtr[mi] = As + (wr * 64 + mi * 16 + (lane & 15)) * 32 + (lane >> 4) * 8;
#pragma unroll
  for (int ni = 0; ni < 4; ++ni)
    bPtr[ni] = Bs + (wc * 64 + ni * 16 + (lane & 15)) * 32 + (lane >> 4) * 8;

  for (int kt = 0; kt < K / 32; ++kt) {
    const int ko = kt * 32;
    gld16(Ap + ko,          lA0);
    gld16(Ap + ko + 64 * K, lA1);
    gld16(Bp + ko,          lB0);
    gld16(Bp + ko + 64 * K, lB1);
    __syncthreads();
    bf16x8 af[4], bfr[4];
#pragma unroll
    for (int mi = 0; mi < 4; ++mi) af[mi] = *(const bf16x8*)aPtr[mi];
#pragma unroll
    for (int ni = 0; ni < 4; ++ni) bfr[ni] = *(const bf16x8*)bPtr[ni];
#pragma unroll
    for (int mi = 0; mi < 4; ++mi)
#pragma unroll
      for (int ni = 0; ni < 4; ++ni)
        acc[mi][ni] = __builtin_amdgcn_mfma_f32_16x16x32_bf16(af[mi], bfr[ni],
                                                              acc[mi][ni], 0, 0, 0);
    __syncthreads();
  }

  // ---- epilogue: rotate q (not K): qtilde = qd*cos + sgn*q[c^1]*sin ----
  const int b  = bm >> 4;
  const int h  = bn;
  const int s0 = (bm & 15) * 128;
  const int rg = lane >> 4, l15 = lane & 15;
  const float* qb = qv + ((size_t)b * 16 + h) * 128;
  float rowsum[4][4];
#pragma unroll
  for (int mi = 0; mi < 4; ++mi)
#pragma unroll
    for (int r = 0; r < 4; ++r) rowsum[mi][r] = 0.f;

  if (wc == 0) {   // cols 0..63: RoPE region
    const float sgn = (l15 & 1) ? -1.f : 1.f;
#pragma unroll
    for (int ni = 0; ni < 4; ++ni) {
      const int c = ni * 16 + l15;
      const float qd  = qb[c];
      const float qps = sgn * qb[c ^ 1];
      const int i = c >> 1;
#pragma unroll
      for (int mi = 0; mi < 4; ++mi)
#pragma unroll
        for (int r = 0; r < 4; ++r) {
          const int t = s0 + wr * 64 + mi * 16 + rg * 4 + r;
          const float2 sc = tab[t * 32 + i];
          rowsum[mi][r] += acc[mi][ni][r] * (qd * sc.y + qps * sc.x);
        }
    }
  } else {         // cols 64..127: plain dot
#pragma unroll
    for (int ni = 0; ni < 4; ++ni) {
      const float qd = qb[64 + ni * 16 + l15];
#pragma unroll
      for (int mi = 0; mi < 4; ++mi)
#pragma unroll
        for (int r = 0; r < 4; ++r)
          rowsum[mi][r] += acc[mi][ni][r] * qd;
    }
  }
#pragma unroll
  for (int mi = 0; mi < 4; ++mi)
#pragma unroll
    for (int r = 0; r < 4; ++r) {
      float v = rowsum[mi][r];
      v += __shfl_xor(v, 1);
      v += __shfl_xor(v, 2);
      v += __shfl_xor(v, 4);
      v += __shfl_xor(v, 8);
      rowsum[mi][r] = v;
    }
  __shared__ float sS[4][64];
  if (l15 == 0) {
#pragma unroll
    for (int mi = 0; mi < 4; ++mi)
#pragma unroll
      for (int r = 0; r < 4; ++r)
        sS[wave][mi * 16 + rg * 4 + r] = rowsum[mi][r];
  }
  __syncthreads();
  if (tid < 128) {
    const int half = tid >> 6, rl = tid & 63;
    scores[((size_t)b * 16 + h) * 2048 + s0 + tid] =
        sS[half * 2][rl] + sS[half * 2 + 1][rl];
  }
}

// ---------------------------------------------------------------------------
// 4. attn_z: per (b,h): add kb.qtilde bias term, block max, w=exp(s-gmax)
//    -> sw_t[b][t][16h], Z[bh].  128 blocks.
//    kbdot[t] = R + sum_i cos[t,i]*P[i] + sin[t,i]*Qa[i]
// ---------------------------------------------------------------------------
__global__ __launch_bounds__(256) void attn_z_kernel(
    const float* __restrict__ scores, const float* __restrict__ qv,
    const float* __restrict__ kb, const float2* __restrict__ tab,
    float* __restrict__ sw_t, float* __restrict__ Z) {
  const int bh = blockIdx.x, b = bh >> 4, h = bh & 15;
  const int tid = threadIdx.x, lane = tid & 63, wave = tid >> 6;
  __shared__ float sP[32], sQa[32];
  __shared__ float sS[2048];
  __shared__ float red[4];
  __shared__ float sRv;
  if (wave == 0) {
    if (lane < 32) {
      const float ke = kb[h * 128 + 2 * lane], ko = kb[h * 128 + 2 * lane + 1];
      const float qe = qv[(size_t)bh * 128 + 2 * lane];
      const float qo = qv[(size_t)bh * 128 + 2 * lane + 1];
      sP[lane]  = ke * qe + ko * qo;
      sQa[lane] = ke * qo - ko * qe;
    }
  } else if (wave == 1) {
    float s = kb[h * 128 + 64 + lane] * qv[(size_t)bh * 128 + 64 + lane];
    for (int m = 1; m < 64; m <<= 1) s += __shfl_xor(s, m);
    if (lane == 0) sRv = s;
  }
  __syncthreads();
  const float R = sRv;
  float lmax = -3.4e38f;
  for (int t = tid; t < 2048; t += 256) {
    float kd = R;
    const float4* tp = (const float4*)(tab + t * 32);
#pragma unroll
    for (int i = 0; i < 16; ++i) {
      const float4 v = tp[i];   // sin2i, cos2i, sin2i+1, cos2i+1
      kd += v.y * sP[2 * i] + v.x * sQa[2 * i];
      kd += v.w * sP[2 * i + 1] + v.z * sQa[2 * i + 1];
    }
    const float sc = scores[(size_t)bh * 2048 + t] + kd;
    sS[t] = sc;
    lmax = fmaxf(lmax, sc);
  }
  for (int m = 1; m < 64; m <<= 1) lmax = fmaxf(lmax, __shfl_xor(lmax, m));
  if (lane == 0) red[wave] = lmax;
  __syncthreads();
  const float gmax = fmaxf(fmaxf(red[0], red[1]), fmaxf(red[2], red[3]));
  float lsum = 0.f;
  for (int t = tid; t < 2048; t += 256) {
    const float w = __expf(sS[t] - gmax);
    sw_t[((size_t)b * 2048 + t) * 16 + h] = w;
    lsum += w;
  }
  for (int m = 1; m < 64; m <<= 1) lsum += __shfl_xor(lsum, m);
  __syncthreads();
  if (lane == 0) red[wave] = lsum;
  __syncthreads();
  if (tid == 0) Z[bh] = red[0] + red[1] + red[2] + red[3];
}

// ---------------------------------------------------------------------------
// 5. attn_wsum: part[tc][b][h][e] = sum_{t in chunk} w[b,t,h]*hs[b,t,e].
//    w staged in LDS (8 KB), same-address broadcast reads.
// ---------------------------------------------------------------------------
__global__ __launch_bounds__(256) void attn_wsum_kernel(
    const unsigned short* __restrict__ hs, const float* __restrict__ sw_t,
    float* __restrict__ part) {
  const int b = blockIdx.x, ech = blockIdx.y, tc = blockIdx.z;
  const int tid = threadIdx.x;
  const int e = ech * 512 + tid * 2;
  __shared__ float sw[128 * 16];
  {
    const float4* src = (const float4*)(sw_t + ((size_t)b * 2048 + tc * 128) * 16);
    float4* dst = (float4*)sw;
    dst[tid] = src[tid];
    dst[tid + 256] = src[tid + 256];
  }
  __syncthreads();
  float a0[16], a1[16];
#pragma unroll
  for (int h = 0; h < 16; ++h) { a0[h] = 0.f; a1[h] = 0.f; }
  const unsigned short* hp = hs + ((size_t)b * 2048 + tc * 128) * 2048 + e;
#pragma unroll 2
  for (int tt = 0; tt < 128; ++tt) {
    const unsigned hv = *(const unsigned*)(hp + (size_t)tt * 2048);
    const float h0 = __uint_as_float(hv << 16);
    const float h1 = __uint_as_float(hv & 0xffff0000u);
    const float4 w0 = *(const float4*)(sw + tt * 16 + 0);
    const float4 w1 = *(const float4*)(sw + tt * 16 + 4);
    const float4 w2 = *(const float4*)(sw + tt * 16 + 8);
    const float4 w3 = *(const float4*)(sw + tt * 16 + 12);
    const float wv[16] = {w0.x, w0.y, w0.z, w0.w, w1.x, w1.y, w1.z, w1.w,
                          w2.x, w2.y, w2.z, w2.w, w3.x, w3.y, w3.z, w3.w};
#pragma unroll
    for (int h = 0; h < 16; ++h) {
      a0[h] += wv[h] * h0;
      a1[h] += wv[h] * h1;
    }
  }
#pragma unroll
  for (int h = 0; h < 16; ++h) {
    float2 st = {a0[h], a1[h]};
    *(float2*)(part + (((size_t)tc * 8 + b) * 16 + h) * 2048 + e) = st;
  }
}

// ---------------------------------------------------------------------------
// 6. attn_comb: wsumN[bh][e] = (sum_tc part) / Z[bh].  128 blocks.
// ---------------------------------------------------------------------------
__global__ __launch_bounds__(256) void attn_comb_kernel(
    const float* __restrict__ part, const float* __restrict__ Z,
    float* __restrict__ wsumN) {
  const int bh = blockIdx.x, b = bh >> 4, h = bh & 15;
  const float zi = 1.f / Z[bh];
  for (int e = threadIdx.x; e < 2048; e += 256) {
    float s = 0.f;
#pragma unroll
    for (int tc = 0; tc < 16; ++tc)
      s += part[(((size_t)tc * 8 + b) * 16 + h) * 2048 + e];
    wsumN[(size_t)bh * 2048 + e] = s * zi;
  }
}

// ---------------------------------------------------------------------------
// 7. attn_vgemv: aout[bh][d] = v_w[h*128+d] . wsumN[bh] + v_b[h*128+d]
// ---------------------------------------------------------------------------
__global__ __launch_bounds__(256) void attn_vgemv_kernel(
    const float* __restrict__ vw, const float* __restrict__ vb,
    const float* __restrict__ wsumN, float* __restrict__ aout) {
  const int tid = threadIdx.x, lane = tid & 63, wave = tid >> 6;
  const int gw = blockIdx.x * 4 + wave;
  const int h = gw >> 7, d = gw & 127;
  const float* vr = vw + (size_t)gw * 2048;
  float p[8] = {0, 0, 0, 0, 0, 0, 0, 0};
#pragma unroll
  for (int it = 0; it < 8; ++it) {
    const int k = it * 256 + lane * 4;
    float4 wv = *(const float4*)(vr + k);
#pragma unroll
    for (int b = 0; b < 8; ++b) {
      float4 xv = *(const float4*)(wsumN + ((size_t)b * 16 + h) * 2048 + k);
      p[b] += wv.x * xv.x + wv.y * xv.y + wv.z * xv.z + wv.w * xv.w;
    }
  }
#pragma unroll
  for (int b = 0; b < 8; ++b)
    for (int m = 1; m < 64; m <<= 1) p[b] += __shfl_xor(p[b], m);
  if (lane == 0) {
    const float bb = vb[gw];
#pragma unroll
    for (int b = 0; b < 8; ++b)
      aout[((size_t)b * 16 + h) * 128 + d] = p[b] + bb;
  }
}

// ---------------------------------------------------------------------------
extern "C" void kernel_launch(void* const* d_in, const int* in_sizes, int n_in,
                              void* d_out, int out_size, void* d_ws, size_t ws_size,
                              hipStream_t stream) {
  (void)in_sizes; (void)n_in; (void)out_size; (void)ws_size;
  const float* hidden = (const float*)d_in[0];
  const int*   ids    = (const int*)d_in[1];
  const float* ln_w   = (const float*)d_in[2];
  const float* ln_b   = (const float*)d_in[3];
  const float* q_w    = (const float*)d_in[4];
  const float* q_b    = (const float*)d_in[5];
  const float* k_w    = (const float*)d_in[6];
  const float* k_b    = (const float*)d_in[7];
  const float* v_w    = (const float*)d_in[8];
  const float* v_b    = (const float*)d_in[9];
  const float* out_w  = (const float*)d_in[10];
  const float* out_b  = (const float*)d_in[11];
  float* out = (float*)d_out;

  char* ws = (char*)d_ws;
  unsigned short* hs  = (unsigned short*)ws; ws += (size_t)16384 * 2048 * 2;  // 64 MB
  unsigned short* Wk  = (unsigned short*)ws; ws += (size_t)2048 * 2048 * 2;   // 8 MB
  float2* sctab = (float2*)ws; ws += (size_t)2048 * 32 * 8;                   // 512 KB
  float* qv     = (float*)ws; ws += (size_t)8 * 2048 * 4;
  float* hl     = (float*)ws; ws += (size_t)8 * 2048 * 4;
  float* aout   = (float*)ws; ws += (size_t)8 * 2048 * 4;
  float* scores = (float*)ws; ws += (size_t)128 * 2048 * 4;                   // 1 MB
  float* sw_t   = (float*)ws; ws += (size_t)8 * 2048 * 16 * 4;                // 1 MB
  float* Zb     = (float*)ws; ws += 128 * 4;
  float* part   = (float*)ws; ws += (size_t)16 * 8 * 16 * 2048 * 4;           // 16 MB
  float* wsumN  = (float*)ws; ws += (size_t)128 * 2048 * 4;                   // 1 MB

  prep_kernel<<<20744, 256, 0, stream>>>(hidden, ids, ln_w, ln_b, k_w,
                                         hs, Wk, sctab, hl);
  gemv8_kernel<<<512, 256, 0, stream>>>(hl, q_w, q_b, qv);
  gemm_kscore_kernel<<<dim3(128, 16), 256, 0, stream>>>(hs, Wk, qv, sctab,
                                                        scores);
  attn_z_kernel<<<128, 256, 0, stream>>>(scores, qv, k_b, sctab, sw_t, Zb);
  attn_wsum_kernel<<<dim3(8, 4, 16), 256, 0, stream>>>(hs, sw_t, part);
  attn_comb_kernel<<<128, 256, 0, stream>>>(part, Zb, wsumN);
  attn_vgemv_kernel<<<512, 256, 0, stream>>>(v_w, v_b, wsumN, aout);
  gemv8_kernel<<<512, 256, 0, stream>>>(aout, out_w, out_b, out);
}

// Round 6
// 493.549 us; speedup vs baseline: 1.0778x; 1.0778x over previous
//
#include <hip/hip_runtime.h>
#include <hip/hip_bf16.h>
#include <cstdint>
#include <cstddef>

// ---------------------------------------------------------------------------
// NostARHeadAttention: LN -> {Q(last), K} proj -> RoPE(K) -> 1-query attn
// with V-elimination (out_head = v_w_head @ softmax-weighted sum of hs + v_b).
// R5: GEMM epilogue now completes softmax numerator: bias + q-rotation dot +
// exp(sc-40) -> sw_t + atomicAdd Z.  attn_z deleted (7 launches).
// launch_bounds back to natural 128 VGPR (R4's (256,5) forced 48-VGPR spills:
// WRITE_SIZE 44 MB of scratch).
// ---------------------------------------------------------------------------

using bf16x8 = __attribute__((ext_vector_type(8))) __bf16;
using f32x4  = __attribute__((ext_vector_type(4))) float;

__device__ __forceinline__ unsigned short f2bf(float f) {
  unsigned u = __float_as_uint(f);
  u += 0x7fffu + ((u >> 16) & 1u);   // RNE
  return (unsigned short)(u >> 16);
}

__device__ __forceinline__ void gld16(const void* g, void* l) {
  __builtin_amdgcn_global_load_lds((__attribute__((address_space(1))) void*)g,
                                   (__attribute__((address_space(3))) void*)l,
                                   16, 0, 0);
}

// ---------------------------------------------------------------------------
// 1. prep: fused ln (blocks 0..16383) + k_w f2bf (16384..20479) +
//    sctab (20480..20735) + ix+hlast+Z-zero (20736..20743).
// ---------------------------------------------------------------------------
__global__ __launch_bounds__(256) void prep_kernel(
    const float* __restrict__ hidden, const int* __restrict__ ids,
    const float* __restrict__ gw, const float* __restrict__ gb,
    const float* __restrict__ kw, unsigned short* __restrict__ hs,
    unsigned short* __restrict__ Wk, float2* __restrict__ tab,
    float* __restrict__ hl, float* __restrict__ Z) {
  const int blk = blockIdx.x, tid = threadIdx.x;
  const int wave = tid >> 6, lane = tid & 63;

  if (blk < 16384) {                       // ---- LayerNorm row -> bf16
    const size_t row = blk;
    const float* xr = hidden + row * 2048;
    float4 a = ((const float4*)xr)[tid];
    float4 b = ((const float4*)xr)[tid + 256];
    float s  = a.x + a.y + a.z + a.w + b.x + b.y + b.z + b.w;
    float ss = a.x*a.x + a.y*a.y + a.z*a.z + a.w*a.w +
               b.x*b.x + b.y*b.y + b.z*b.z + b.w*b.w;
    for (int m = 1; m < 64; m <<= 1) { s += __shfl_xor(s, m); ss += __shfl_xor(ss, m); }
    __shared__ float rs[4], rss[4];
    if (lane == 0) { rs[wave] = s; rss[wave] = ss; }
    __syncthreads();
    s  = rs[0] + rs[1] + rs[2] + rs[3];
    ss = rss[0] + rss[1] + rss[2] + rss[3];
    const float mu = s * (1.f / 2048.f);
    const float var = ss * (1.f / 2048.f) - mu * mu;
    const float r = rsqrtf(var + 1e-5f);
    const int i0 = tid * 4, i1 = 1024 + tid * 4;
    ushort4 p0 = {f2bf((a.x - mu) * r * gw[i0 + 0] + gb[i0 + 0]),
                  f2bf((a.y - mu) * r * gw[i0 + 1] + gb[i0 + 1]),
                  f2bf((a.z - mu) * r * gw[i0 + 2] + gb[i0 + 2]),
                  f2bf((a.w - mu) * r * gw[i0 + 3] + gb[i0 + 3])};
    ushort4 p1 = {f2bf((b.x - mu) * r * gw[i1 + 0] + gb[i1 + 0]),
                  f2bf((b.y - mu) * r * gw[i1 + 1] + gb[i1 + 1]),
                  f2bf((b.z - mu) * r * gw[i1 + 2] + gb[i1 + 2]),
                  f2bf((b.w - mu) * r * gw[i1 + 3] + gb[i1 + 3])};
    *(ushort4*)(hs + row * 2048 + i0) = p0;
    *(ushort4*)(hs + row * 2048 + i1) = p1;
  } else if (blk < 20480) {                // ---- k_w fp32 -> bf16
    const size_t i = (size_t)(blk - 16384) * 256 + tid;
    float4 v = ((const float4*)kw)[i];
    ushort4 o = {f2bf(v.x), f2bf(v.y), f2bf(v.z), f2bf(v.w)};
    ((ushort4*)Wk)[i] = o;
  } else if (blk < 20736) {                // ---- sin/cos table (8 t / block)
    const int t = (blk - 20480) * 8 + (tid >> 5);
    const int i = tid & 31;
    const float inv = exp2f(-(float)i * (13.287712379549449f / 32.f));
    const float ang = (float)t * inv;
    tab[t * 32 + i] = make_float2(sinf(ang), cosf(ang));
  } else {                                 // ---- last-token index + LN + Z=0
    const int b = blk - 20736;
    if (tid < 16) Z[b * 16 + tid] = 0.f;
    int best = -1;
    for (int t = tid; t < 2048; t += 256)
      if (ids[b * 2048 + t] != 50257) best = (t > best) ? t : best;
    for (int m = 1; m < 64; m <<= 1) {
      int o = __shfl_xor(best, m);
      best = (o > best) ? o : best;
    }
    __shared__ int rb[4];
    if (lane == 0) rb[wave] = best;
    __syncthreads();
    int ix = rb[0];
    for (int w = 1; w < 4; ++w) ix = (rb[w] > ix) ? rb[w] : ix;
    ix = (ix < 0) ? 0 : ix;
    const float* xr = hidden + ((size_t)b * 2048 + ix) * 2048;
    float4 a = ((const float4*)xr)[tid];
    float4 c = ((const float4*)xr)[tid + 256];
    float s  = a.x + a.y + a.z + a.w + c.x + c.y + c.z + c.w;
    float ss = a.x*a.x + a.y*a.y + a.z*a.z + a.w*a.w +
               c.x*c.x + c.y*c.y + c.z*c.z + c.w*c.w;
    for (int m = 1; m < 64; m <<= 1) { s += __shfl_xor(s, m); ss += __shfl_xor(ss, m); }
    __shared__ float rs2[4], rss2[4];
    if (lane == 0) { rs2[wave] = s; rss2[wave] = ss; }
    __syncthreads();
    s  = rs2[0] + rs2[1] + rs2[2] + rs2[3];
    ss = rss2[0] + rss2[1] + rss2[2] + rss2[3];
    const float mu = s * (1.f / 2048.f);
    const float var = ss * (1.f / 2048.f) - mu * mu;
    const float r = rsqrtf(var + 1e-5f);
    const int i0 = tid * 4, i1 = 1024 + tid * 4;
    float* yo = hl + (size_t)b * 2048;
    yo[i0 + 0] = (a.x - mu) * r * gw[i0 + 0] + gb[i0 + 0];
    yo[i0 + 1] = (a.y - mu) * r * gw[i0 + 1] + gb[i0 + 1];
    yo[i0 + 2] = (a.z - mu) * r * gw[i0 + 2] + gb[i0 + 2];
    yo[i0 + 3] = (a.w - mu) * r * gw[i0 + 3] + gb[i0 + 3];
    yo[i1 + 0] = (c.x - mu) * r * gw[i1 + 0] + gb[i1 + 0];
    yo[i1 + 1] = (c.y - mu) * r * gw[i1 + 1] + gb[i1 + 1];
    yo[i1 + 2] = (c.z - mu) * r * gw[i1 + 2] + gb[i1 + 2];
    yo[i1 + 3] = (c.w - mu) * r * gw[i1 + 3] + gb[i1 + 3];
  }
}

// ---------------------------------------------------------------------------
// 2. GEMV: Y[8][2048] = X[8][2048] @ W^T + bias (fp32), 512 blocks.
// ---------------------------------------------------------------------------
__global__ __launch_bounds__(256) void gemv8_kernel(const float* __restrict__ X,
                                                    const float* __restrict__ W,
                                                    const float* __restrict__ bias,
                                                    float* __restrict__ Y) {
  const int tid = threadIdx.x, lane = tid & 63, wave = tid >> 6;
  const int e = blockIdx.x * 4 + wave;
  const float* wr = W + (size_t)e * 2048;
  float p[8] = {0, 0, 0, 0, 0, 0, 0, 0};
#pragma unroll
  for (int it = 0; it < 8; ++it) {
    const int k = it * 256 + lane * 4;
    float4 wv = *(const float4*)(wr + k);
#pragma unroll
    for (int b = 0; b < 8; ++b) {
      float4 xv = *(const float4*)(X + b * 2048 + k);
      p[b] += wv.x * xv.x + wv.y * xv.y + wv.z * xv.z + wv.w * xv.w;
    }
  }
#pragma unroll
  for (int b = 0; b < 8; ++b)
    for (int m = 1; m < 64; m <<= 1) p[b] += __shfl_xor(p[b], m);
  if (lane == 0) {
    const float bb = bias[e];
#pragma unroll
    for (int b = 0; b < 8; ++b) Y[(size_t)b * 2048 + e] = p[b] + bb;
  }
}

// ---------------------------------------------------------------------------
// 3. K GEMM + full fused epilogue: bias + q-rotation dot + exp(sc-40)
//    -> sw_t[b][t][16h] and atomicAdd Z[bh].
// ---------------------------------------------------------------------------
__global__ __launch_bounds__(256) void gemm_kscore_kernel(
    const unsigned short* __restrict__ A, const unsigned short* __restrict__ W,
    const float* __restrict__ kb, const float* __restrict__ qv,
    const float2* __restrict__ tab, float* __restrict__ sw_t,
    float* __restrict__ Z) {
  constexpr int K = 2048;
  __shared__ unsigned short As[128 * 32];
  __shared__ unsigned short Bs[128 * 32];
  const int tid = threadIdx.x;
  const int lane = tid & 63, wave = tid >> 6;
  const int wr = wave >> 1, wc = wave & 1;
  const int bm = blockIdx.x, bn = blockIdx.y;

  const unsigned short* Ap = A + ((size_t)(bm * 128 + (tid >> 2))) * K + (tid & 3) * 8;
  const unsigned short* Bp = W + ((size_t)(bn * 128 + (tid >> 2))) * K + (tid & 3) * 8;
  unsigned short* lA0 = As + wave * 512;
  unsigned short* lA1 = As + 2048 + wave * 512;
  unsigned short* lB0 = Bs + wave * 512;
  unsigned short* lB1 = Bs + 2048 + wave * 512;

  f32x4 acc[4][4];
#pragma unroll
  for (int i = 0; i < 4; ++i)
#pragma unroll
    for (int j = 0; j < 4; ++j) acc[i][j] = (f32x4){0.f, 0.f, 0.f, 0.f};

  const unsigned short* aPtr[4];
  const unsigned short* bPtr[4];
#pragma unroll
  for (int mi = 0; mi < 4; ++mi)
    aPtr[mi] = As + (wr * 64 + mi * 16 + (lane & 15)) * 32 + (lane >> 4) * 8;
#pragma unroll
  for (int ni = 0; ni < 4; ++ni)
    bPtr[ni] = Bs + (wc * 64 + ni * 16 + (lane & 15)) * 32 + (lane >> 4) * 8;

  for (int kt = 0; kt < K / 32; ++kt) {
    const int ko = kt * 32;
    gld16(Ap + ko,          lA0);
    gld16(Ap + ko + 64 * K, lA1);
    gld16(Bp + ko,          lB0);
    gld16(Bp + ko + 64 * K, lB1);
    __syncthreads();
    bf16x8 af[4], bfr[4];
#pragma unroll
    for (int mi = 0; mi < 4; ++mi) af[mi] = *(const bf16x8*)aPtr[mi];
#pragma unroll
    for (int ni = 0; ni < 4; ++ni) bfr[ni] = *(const bf16x8*)bPtr[ni];
#pragma unroll
    for (int mi = 0; mi < 4; ++mi)
#pragma unroll
      for (int ni = 0; ni < 4; ++ni)
        acc[mi][ni] = __builtin_amdgcn_mfma_f32_16x16x32_bf16(af[mi], bfr[ni],
                                                              acc[mi][ni], 0, 0, 0);
    __syncthreads();
  }

  // ---- epilogue: score = sum_c (K[t,c]+kb[c]) * qtilde[t,c]; w = exp(sc-40)
  const int b  = bm >> 4;
  const int h  = bn;
  const int s0 = (bm & 15) * 128;
  const int rg = lane >> 4, l15 = lane & 15;
  const float* qb  = qv + ((size_t)b * 16 + h) * 128;
  const float* kbh = kb + h * 128;
  float rowsum[4][4];
#pragma unroll
  for (int mi = 0; mi < 4; ++mi)
#pragma unroll
    for (int r = 0; r < 4; ++r) rowsum[mi][r] = 0.f;

  if (wc == 0) {   // cols 0..63: RoPE region (rotate q, not K)
    const float sgn = (l15 & 1) ? -1.f : 1.f;
#pragma unroll
    for (int ni = 0; ni < 4; ++ni) {
      const int c = ni * 16 + l15;
      const float qd   = qb[c];
      const float qps  = sgn * qb[c ^ 1];
      const float bias = kbh[c];
      const int i = c >> 1;
#pragma unroll
      for (int mi = 0; mi < 4; ++mi)
#pragma unroll
        for (int r = 0; r < 4; ++r) {
          const int t = s0 + wr * 64 + mi * 16 + rg * 4 + r;
          const float2 sc = tab[t * 32 + i];
          rowsum[mi][r] += (acc[mi][ni][r] + bias) * (qd * sc.y + qps * sc.x);
        }
    }
  } else {         // cols 64..127: plain dot
#pragma unroll
    for (int ni = 0; ni < 4; ++ni) {
      const int c = 64 + ni * 16 + l15;
      const float qd   = qb[c];
      const float bias = kbh[c];
#pragma unroll
      for (int mi = 0; mi < 4; ++mi)
#pragma unroll
        for (int r = 0; r < 4; ++r)
          rowsum[mi][r] += (acc[mi][ni][r] + bias) * qd;
    }
  }
#pragma unroll
  for (int mi = 0; mi < 4; ++mi)
#pragma unroll
    for (int r = 0; r < 4; ++r) {
      float v = rowsum[mi][r];
      v += __shfl_xor(v, 1);
      v += __shfl_xor(v, 2);
      v += __shfl_xor(v, 4);
      v += __shfl_xor(v, 8);
      rowsum[mi][r] = v;
    }
  __shared__ float sS[4][64];
  __shared__ float sWs[2];
  if (l15 == 0) {
#pragma unroll
    for (int mi = 0; mi < 4; ++mi)
#pragma unroll
      for (int r = 0; r < 4; ++r)
        sS[wave][mi * 16 + rg * 4 + r] = rowsum[mi][r];
  }
  __syncthreads();
  if (tid < 128) {
    const int half = tid >> 6, rl = tid & 63;
    const float sc = sS[half * 2][rl] + sS[half * 2 + 1][rl];
    const float w = __expf(sc - 40.f);
    sw_t[((size_t)b * 2048 + s0 + tid) * 16 + h] = w;
    float v = w;
    for (int m = 1; m < 64; m <<= 1) v += __shfl_xor(v, m);
    if (rl == 0) sWs[half] = v;
  }
  __syncthreads();
  if (tid == 0) atomicAdd(&Z[b * 16 + h], sWs[0] + sWs[1]);
}

// ---------------------------------------------------------------------------
// 4. attn_wsum: part[tc][b][h][e] = sum_{t in chunk} w[b,t,h]*hs[b,t,e].
//    w staged in LDS (8 KB), same-address broadcast reads.
// ---------------------------------------------------------------------------
__global__ __launch_bounds__(256) void attn_wsum_kernel(
    const unsigned short* __restrict__ hs, const float* __restrict__ sw_t,
    float* __restrict__ part) {
  const int b = blockIdx.x, ech = blockIdx.y, tc = blockIdx.z;
  const int tid = threadIdx.x;
  const int e = ech * 512 + tid * 2;
  __shared__ float sw[128 * 16];
  {
    const float4* src = (const float4*)(sw_t + ((size_t)b * 2048 + tc * 128) * 16);
    float4* dst = (float4*)sw;
    dst[tid] = src[tid];
    dst[tid + 256] = src[tid + 256];
  }
  __syncthreads();
  float a0[16], a1[16];
#pragma unroll
  for (int h = 0; h < 16; ++h) { a0[h] = 0.f; a1[h] = 0.f; }
  const unsigned short* hp = hs + ((size_t)b * 2048 + tc * 128) * 2048 + e;
#pragma unroll 2
  for (int tt = 0; tt < 128; ++tt) {
    const unsigned hv = *(const unsigned*)(hp + (size_t)tt * 2048);
    const float h0 = __uint_as_float(hv << 16);
    const float h1 = __uint_as_float(hv & 0xffff0000u);
    const float4 w0 = *(const float4*)(sw + tt * 16 + 0);
    const float4 w1 = *(const float4*)(sw + tt * 16 + 4);
    const float4 w2 = *(const float4*)(sw + tt * 16 + 8);
    const float4 w3 = *(const float4*)(sw + tt * 16 + 12);
    const float wv[16] = {w0.x, w0.y, w0.z, w0.w, w1.x, w1.y, w1.z, w1.w,
                          w2.x, w2.y, w2.z, w2.w, w3.x, w3.y, w3.z, w3.w};
#pragma unroll
    for (int h = 0; h < 16; ++h) {
      a0[h] += wv[h] * h0;
      a1[h] += wv[h] * h1;
    }
  }
#pragma unroll
  for (int h = 0; h < 16; ++h) {
    float2 st = {a0[h], a1[h]};
    *(float2*)(part + (((size_t)tc * 8 + b) * 16 + h) * 2048 + e) = st;
  }
}

// ---------------------------------------------------------------------------
// 5. attn_comb: wsumN[bh][e] = (sum_tc part) / Z[bh].  128 blocks.
// ---------------------------------------------------------------------------
__global__ __launch_bounds__(256) void attn_comb_kernel(
    const float* __restrict__ part, const float* __restrict__ Z,
    float* __restrict__ wsumN) {
  const int bh = blockIdx.x, b = bh >> 4, h = bh & 15;
  const float zi = 1.f / Z[bh];
  for (int e = threadIdx.x; e < 2048; e += 256) {
    float s = 0.f;
#pragma unroll
    for (int tc = 0; tc < 16; ++tc)
      s += part[(((size_t)tc * 8 + b) * 16 + h) * 2048 + e];
    wsumN[(size_t)bh * 2048 + e] = s * zi;
  }
}

// ---------------------------------------------------------------------------
// 6. attn_vgemv: aout[bh][d] = v_w[h*128+d] . wsumN[bh] + v_b[h*128+d]
// ---------------------------------------------------------------------------
__global__ __launch_bounds__(256) void attn_vgemv_kernel(
    const float* __restrict__ vw, const float* __restrict__ vb,
    const float* __restrict__ wsumN, float* __restrict__ aout) {
  const int tid = threadIdx.x, lane = tid & 63, wave = tid >> 6;
  const int gw = blockIdx.x * 4 + wave;
  const int h = gw >> 7, d = gw & 127;
  const float* vr = vw + (size_t)gw * 2048;
  float p[8] = {0, 0, 0, 0, 0, 0, 0, 0};
#pragma unroll
  for (int it = 0; it < 8; ++it) {
    const int k = it * 256 + lane * 4;
    float4 wv = *(const float4*)(vr + k);
#pragma unroll
    for (int b = 0; b < 8; ++b) {
      float4 xv = *(const float4*)(wsumN + ((size_t)b * 16 + h) * 2048 + k);
      p[b] += wv.x * xv.x + wv.y * xv.y + wv.z * xv.z + wv.w * xv.w;
    }
  }
#pragma unroll
  for (int b = 0; b < 8; ++b)
    for (int m = 1; m < 64; m <<= 1) p[b] += __shfl_xor(p[b], m);
  if (lane == 0) {
    const float bb = vb[gw];
#pragma unroll
    for (int b = 0; b < 8; ++b)
      aout[((size_t)b * 16 + h) * 128 + d] = p[b] + bb;
  }
}

// ---------------------------------------------------------------------------
extern "C" void kernel_launch(void* const* d_in, const int* in_sizes, int n_in,
                              void* d_out, int out_size, void* d_ws, size_t ws_size,
                              hipStream_t stream) {
  (void)in_sizes; (void)n_in; (void)out_size; (void)ws_size;
  const float* hidden = (const float*)d_in[0];
  const int*   ids    = (const int*)d_in[1];
  const float* ln_w   = (const float*)d_in[2];
  const float* ln_b   = (const float*)d_in[3];
  const float* q_w    = (const float*)d_in[4];
  const float* q_b    = (const float*)d_in[5];
  const float* k_w    = (const float*)d_in[6];
  const float* k_b    = (const float*)d_in[7];
  const float* v_w    = (const float*)d_in[8];
  const float* v_b    = (const float*)d_in[9];
  const float* out_w  = (const float*)d_in[10];
  const float* out_b  = (const float*)d_in[11];
  float* out = (float*)d_out;

  char* ws = (char*)d_ws;
  unsigned short* hs  = (unsigned short*)ws; ws += (size_t)16384 * 2048 * 2;  // 64 MB
  unsigned short* Wk  = (unsigned short*)ws; ws += (size_t)2048 * 2048 * 2;   // 8 MB
  float2* sctab = (float2*)ws; ws += (size_t)2048 * 32 * 8;                   // 512 KB
  float* qv     = (float*)ws; ws += (size_t)8 * 2048 * 4;
  float* hl     = (float*)ws; ws += (size_t)8 * 2048 * 4;
  float* aout   = (float*)ws; ws += (size_t)8 * 2048 * 4;
  float* sw_t   = (float*)ws; ws += (size_t)8 * 2048 * 16 * 4;                // 1 MB
  float* Zb     = (float*)ws; ws += 128 * 4;
  float* part   = (float*)ws; ws += (size_t)16 * 8 * 16 * 2048 * 4;           // 16 MB
  float* wsumN  = (float*)ws; ws += (size_t)128 * 2048 * 4;                   // 1 MB

  prep_kernel<<<20744, 256, 0, stream>>>(hidden, ids, ln_w, ln_b, k_w,
                                         hs, Wk, sctab, hl, Zb);
  gemv8_kernel<<<512, 256, 0, stream>>>(hl, q_w, q_b, qv);
  gemm_kscore_kernel<<<dim3(128, 16), 256, 0, stream>>>(hs, Wk, k_b, qv, sctab,
                                                        sw_t, Zb);
  attn_wsum_kernel<<<dim3(8, 4, 16), 256, 0, stream>>>(hs, sw_t, part);
  attn_comb_kernel<<<128, 256, 0, stream>>>(part, Zb, wsumN);
  attn_vgemv_kernel<<<512, 256, 0, stream>>>(v_w, v_b, wsumN, aout);
  gemv8_kernel<<<512, 256, 0, stream>>>(aout, out_w, out_b, out);
}